// Round 1
// baseline (430.733 us; speedup 1.0000x reference)
//
#include <hip/hip_runtime.h>
#include <stdint.h>

#define B_  8
#define T_  512
#define D_  1024
#define H_  16
#define DH  128
#define BH  128          // B_*H_
#define ND  2048         // H_*DH
#define BT  4096         // B_*T_

typedef __attribute__((ext_vector_type(8))) short          short8;
typedef __attribute__((ext_vector_type(8))) __bf16         bf16x8;
typedef __attribute__((ext_vector_type(4))) float          f32x4;
typedef __attribute__((ext_vector_type(4))) unsigned short ushort4v;

static __device__ __forceinline__ unsigned short f2bf(float f) {
  unsigned u = __builtin_bit_cast(unsigned, f);
  u += 0x7FFFu + ((u >> 16) & 1u);           // round-to-nearest-even
  return (unsigned short)(u >> 16);
}
static __device__ __forceinline__ float bf2f(unsigned short h) {
  unsigned u = ((unsigned)h) << 16;
  return __builtin_bit_cast(float, u);
}
static __device__ __forceinline__ f32x4 mfma16(short8 a, short8 b, f32x4 c) {
  return __builtin_amdgcn_mfma_f32_16x16x32_bf16(
      __builtin_bit_cast(bf16x8, a), __builtin_bit_cast(bf16x8, b), c, 0, 0, 0);
}

// ---- staging helpers: 64x64 tile into LDS [64][72] (pad keeps 16B align, 2-way banks) ----
static __device__ __forceinline__ void stage_b16(unsigned short (*dst)[72],
                                                 const unsigned short* __restrict__ src,
                                                 long stride, int tid) {
#pragma unroll
  for (int it = 0; it < 2; ++it) {
    int chunk = tid + it * 256;            // 0..511
    int r = chunk >> 3, c8 = (chunk & 7) * 8;
    *(short8*)&dst[r][c8] = *(const short8*)(src + (long)r * stride + c8);
  }
}
static __device__ __forceinline__ void stage_f32(unsigned short (*dst)[72],
                                                 const float* __restrict__ src,
                                                 long stride, int tid) {
#pragma unroll
  for (int it = 0; it < 4; ++it) {
    int chunk = tid + it * 256;            // 0..1023
    int r = chunk >> 4, c4 = (chunk & 15) * 4;
    f32x4 v = *(const f32x4*)(src + (long)r * stride + c4);
    unsigned short* p = &dst[r][c4];
    p[0] = f2bf(v.x); p[1] = f2bf(v.y); p[2] = f2bf(v.z); p[3] = f2bf(v.w);
  }
}
// transpose-stage: src fp32 rows are K(=k) x >=64 cols(=d); dst[d][k]
static __device__ __forceinline__ void stage_f32_t(unsigned short (*dst)[72],
                                                   const float* __restrict__ src,
                                                   long stride, int tid) {
#pragma unroll
  for (int it = 0; it < 4; ++it) {
    int chunk = tid + it * 256;
    int k = chunk >> 4, d4 = (chunk & 15) * 4;
    f32x4 v = *(const f32x4*)(src + (long)k * stride + d4);
    dst[d4 + 0][k] = f2bf(v.x);
    dst[d4 + 1][k] = f2bf(v.y);
    dst[d4 + 2][k] = f2bf(v.z);
    dst[d4 + 3][k] = f2bf(v.w);
  }
}

// per-wave 32x32 (2x2 frags of 16x16) over one staged BK=64 step
static __device__ __forceinline__ void gemm_step(const unsigned short (*As)[72],
                                                 const unsigned short (*Bs)[72],
                                                 int wm, int wn, int lrow, int lk8,
                                                 f32x4 acc[2][2]) {
#pragma unroll
  for (int ks = 0; ks < 64; ks += 32) {
    short8 a0 = *(const short8*)&As[wm * 32 + 0  + lrow][ks + lk8];
    short8 a1 = *(const short8*)&As[wm * 32 + 16 + lrow][ks + lk8];
    short8 b0 = *(const short8*)&Bs[wn * 32 + 0  + lrow][ks + lk8];
    short8 b1 = *(const short8*)&Bs[wn * 32 + 16 + lrow][ks + lk8];
    acc[0][0] = mfma16(a0, b0, acc[0][0]);
    acc[0][1] = mfma16(a0, b1, acc[0][1]);
    acc[1][0] = mfma16(a1, b0, acc[1][0]);
    acc[1][1] = mfma16(a1, b1, acc[1][1]);
  }
}

#define GEMM_IDS                                  \
  const int tid = threadIdx.x;                    \
  const int lane = tid & 63;                      \
  const int wm = tid >> 7, wn = (tid >> 6) & 1;   \
  const int lrow = lane & 15, lk8 = (lane >> 4) * 8;

// ------------------- prep kernels -------------------
__global__ __launch_bounds__(256) void k_cvt(const float* __restrict__ in,
                                             unsigned short* __restrict__ outp, int n4) {
  int i = blockIdx.x * 256 + threadIdx.x;
  if (i >= n4) return;
  f32x4 v = ((const f32x4*)in)[i];
  ushort4v o;
  o.x = f2bf(v.x); o.y = f2bf(v.y); o.z = f2bf(v.z); o.w = f2bf(v.w);
  ((ushort4v*)outp)[i] = o;
}

// out[c][r] = bf16(in[r][c]); R,C multiples of 32
__global__ __launch_bounds__(256) void k_transcvt(const float* __restrict__ in,
                                                  unsigned short* __restrict__ outp,
                                                  int R, int C) {
  __shared__ float tile[32][33];
  int c0 = blockIdx.x * 32, r0 = blockIdx.y * 32;
  int tx = threadIdx.x & 31, ty = threadIdx.x >> 5;   // 8 rows/iter
#pragma unroll
  for (int i = 0; i < 32; i += 8)
    tile[ty + i][tx] = in[(long)(r0 + ty + i) * C + (c0 + tx)];
  __syncthreads();
#pragma unroll
  for (int i = 0; i < 32; i += 8)
    outp[(long)(c0 + ty + i) * R + (r0 + tx)] = f2bf(tile[tx][ty + i]);
}

// Vb[t][bh][d] -> Vt[bh][d][t]
__global__ __launch_bounds__(256) void k_vtrans(const unsigned short* __restrict__ vin,
                                                unsigned short* __restrict__ vout) {
  __shared__ unsigned short tile[32][33];
  int bh = blockIdx.z;
  int t0 = blockIdx.x * 32, d0 = blockIdx.y * 32;
  int tx = threadIdx.x & 31, ty = threadIdx.x >> 5;
#pragma unroll
  for (int i = 0; i < 32; i += 8)
    tile[ty + i][tx] = vin[((long)(t0 + ty + i) * BH + bh) * DH + (d0 + tx)];
  __syncthreads();
#pragma unroll
  for (int i = 0; i < 32; i += 8)
    vout[((long)bh * DH + (d0 + ty + i)) * T_ + (t0 + tx)] = tile[tx][ty + i];
}

// ------------------- QKV projection: [Q|K|V] = Xb @ WT^T + bias -------------------
__global__ __launch_bounds__(256) void k_proj(const unsigned short* __restrict__ Xb,
                                              const unsigned short* __restrict__ WT,
                                              const float* __restrict__ bq,
                                              const float* __restrict__ bk,
                                              const float* __restrict__ bv,
                                              unsigned short* __restrict__ Qb,
                                              unsigned short* __restrict__ Kb,
                                              unsigned short* __restrict__ Vb) {
  __shared__ unsigned short As[64][72], Bs[64][72];
  GEMM_IDS
  const int m0 = blockIdx.y * 64, n0 = blockIdx.x * 64;
  f32x4 acc[2][2] = {};
  for (int kk = 0; kk < D_; kk += 64) {
    stage_b16(As, Xb + (long)m0 * D_ + kk, D_, tid);
    stage_b16(Bs, WT + (long)n0 * D_ + kk, D_, tid);
    __syncthreads();
    gemm_step(As, Bs, wm, wn, lrow, lk8, acc);
    __syncthreads();
  }
  const float* biasp = (n0 < ND) ? bq : (n0 < 2 * ND ? bk : bv);
  unsigned short* dst = (n0 < ND) ? Qb : (n0 < 2 * ND ? Kb : Vb);
#pragma unroll
  for (int ms = 0; ms < 2; ++ms)
#pragma unroll
    for (int ns = 0; ns < 2; ++ns) {
      int n = n0 + wn * 32 + ns * 16 + lrow;
      int nh = n & (ND - 1);
      int h = nh >> 7, dd = nh & (DH - 1);
      float bias = biasp[nh];
#pragma unroll
      for (int r = 0; r < 4; ++r) {
        int m = m0 + wm * 32 + ms * 16 + (lane >> 4) * 4 + r;
        int b = m >> 9, t = m & (T_ - 1);
        dst[((long)t * BH + (b * H_ + h)) * DH + dd] = f2bf(acc[ms][ns][r] + bias);
      }
    }
}

// ------------------- pos-k: att[q][bh][k] = Q[q][bh][:] . Pk[q][k][:] -------------------
__global__ __launch_bounds__(256) void k_posk(const unsigned short* __restrict__ Qb,
                                              const float* __restrict__ Pk,
                                              unsigned short* __restrict__ att) {
  const int q = blockIdx.z, m0 = blockIdx.y * 64, k0 = blockIdx.x * 64;
  if (k0 > q) return;
  __shared__ unsigned short As[64][72], Bs[64][72];
  GEMM_IDS
  f32x4 acc[2][2] = {};
  const unsigned short* Asrc = Qb + (long)q * BH * DH + (long)m0 * DH;
  const float* Bsrc = Pk + ((long)q * T_ + k0) * DH;
  for (int kk = 0; kk < DH; kk += 64) {
    stage_b16(As, Asrc + kk, DH, tid);
    stage_f32(Bs, Bsrc + kk, DH, tid);
    __syncthreads();
    gemm_step(As, Bs, wm, wn, lrow, lk8, acc);
    __syncthreads();
  }
#pragma unroll
  for (int ms = 0; ms < 2; ++ms)
#pragma unroll
    for (int ns = 0; ns < 2; ++ns) {
      int k = k0 + wn * 32 + ns * 16 + lrow;
#pragma unroll
      for (int r = 0; r < 4; ++r) {
        int bh = m0 + wm * 32 + ms * 16 + (lane >> 4) * 4 + r;
        att[((long)q * BH + bh) * T_ + k] = f2bf(acc[ms][ns][r]);
      }
    }
}

// ------------------- QK^T, add pos bias, scale -------------------
__global__ __launch_bounds__(256) void k_qk(const unsigned short* __restrict__ Qb,
                                            const unsigned short* __restrict__ Kb,
                                            unsigned short* __restrict__ att) {
  const int bh = blockIdx.z, qt = blockIdx.y, kt = blockIdx.x;
  if (kt > qt) return;
  const int q0 = qt * 64, k0 = kt * 64;
  __shared__ unsigned short As[64][72], Bs[64][72];
  GEMM_IDS
  f32x4 acc[2][2] = {};
  const unsigned short* Asrc = Qb + ((long)q0 * BH + bh) * DH;
  const unsigned short* Bsrc = Kb + ((long)k0 * BH + bh) * DH;
  for (int kk = 0; kk < DH; kk += 64) {
    stage_b16(As, Asrc + kk, (long)BH * DH, tid);
    stage_b16(Bs, Bsrc + kk, (long)BH * DH, tid);
    __syncthreads();
    gemm_step(As, Bs, wm, wn, lrow, lk8, acc);
    __syncthreads();
  }
  const float scale = 0.08838834764831845f;   // 1/sqrt(128)
#pragma unroll
  for (int ms = 0; ms < 2; ++ms)
#pragma unroll
    for (int ns = 0; ns < 2; ++ns) {
      int k = k0 + wn * 32 + ns * 16 + lrow;
#pragma unroll
      for (int r = 0; r < 4; ++r) {
        int q = q0 + wm * 32 + ms * 16 + (lane >> 4) * 4 + r;
        long idx = ((long)q * BH + bh) * T_ + k;
        float v = acc[ms][ns][r];
        if (k <= q) v += bf2f(att[idx]);      // pos-k term (only valid/causal region)
        att[idx] = f2bf(v * scale);
      }
    }
}

// ------------------- softmax (in-place, zero beyond diagonal) -------------------
__global__ __launch_bounds__(256) void k_softmax(unsigned short* __restrict__ att) {
  const int lane = threadIdx.x & 63, wave = threadIdx.x >> 6;
  const long row = (long)blockIdx.x * 4 + wave;   // row = q*BH + bh
  const int q = (int)(row >> 7);
  unsigned short* p = att + row * T_;
  short8 v8 = *(const short8*)(p + lane * 8);
  float x[8];
  float m = -3.0e38f;
#pragma unroll
  for (int j = 0; j < 8; ++j) {
    int k = lane * 8 + j;
    x[j] = (k <= q) ? bf2f((unsigned short)v8[j]) : -3.0e38f;
    m = fmaxf(m, x[j]);
  }
#pragma unroll
  for (int off = 32; off >= 1; off >>= 1) m = fmaxf(m, __shfl_xor(m, off, 64));
  float e[8];
  float s = 0.f;
#pragma unroll
  for (int j = 0; j < 8; ++j) {
    int k = lane * 8 + j;
    e[j] = (k <= q) ? __expf(x[j] - m) : 0.f;
    s += e[j];
  }
#pragma unroll
  for (int off = 32; off >= 1; off >>= 1) s += __shfl_xor(s, off, 64);
  float inv = 1.f / s;
  short8 o;
#pragma unroll
  for (int j = 0; j < 8; ++j) o[j] = (short)f2bf(e[j] * inv);
  *(short8*)(p + lane * 8) = o;
}

// ------------------- y = P @ V  (writes Yb) -------------------
__global__ __launch_bounds__(256) void k_attv(const unsigned short* __restrict__ P,
                                              const unsigned short* __restrict__ Vt,
                                              float* __restrict__ Yb) {
  const int bh = blockIdx.z, qt = blockIdx.y, dt = blockIdx.x;
  const int q0 = qt * 64, d0 = dt * 64;
  __shared__ unsigned short As[64][72], Bs[64][72];
  GEMM_IDS
  f32x4 acc[2][2] = {};
  const unsigned short* Asrc = P + ((long)q0 * BH + bh) * T_;
  const unsigned short* Bsrc = Vt + ((long)bh * DH + d0) * T_;
  for (int kt = 0; kt <= qt; ++kt) {
    stage_b16(As, Asrc + kt * 64, (long)BH * T_, tid);
    stage_b16(Bs, Bsrc + kt * 64, T_, tid);
    __syncthreads();
    gemm_step(As, Bs, wm, wn, lrow, lk8, acc);
    __syncthreads();
  }
  const int b = bh >> 4, h = bh & 15;
#pragma unroll
  for (int ms = 0; ms < 2; ++ms)
#pragma unroll
    for (int ns = 0; ns < 2; ++ns) {
      int d = d0 + wn * 32 + ns * 16 + lrow;
#pragma unroll
      for (int r = 0; r < 4; ++r) {
        int q = q0 + wm * 32 + ms * 16 + (lane >> 4) * 4 + r;
        Yb[(long)(b * T_ + q) * ND + h * DH + d] = acc[ms][ns][r];
      }
    }
}

// ------------------- y += P @ pos_v[q]  (RMW on Yb) -------------------
__global__ __launch_bounds__(256) void k_posv(const unsigned short* __restrict__ P,
                                              const float* __restrict__ Pv,
                                              float* __restrict__ Yb) {
  const int q = blockIdx.z, mt = blockIdx.y, dt = blockIdx.x;
  const int m0 = mt * 64, d0 = dt * 64;
  const int ktiles = (q >> 6) + 1;
  __shared__ unsigned short As[64][72], Bs[64][72];
  GEMM_IDS
  f32x4 acc[2][2] = {};
  const unsigned short* Asrc = P + ((long)q * BH + m0) * T_;
  for (int kt = 0; kt < ktiles; ++kt) {
    stage_b16(As, Asrc + kt * 64, T_, tid);
    stage_f32_t(Bs, Pv + ((long)q * T_ + kt * 64) * DH + d0, DH, tid);
    __syncthreads();
    gemm_step(As, Bs, wm, wn, lrow, lk8, acc);
    __syncthreads();
  }
#pragma unroll
  for (int ms = 0; ms < 2; ++ms)
#pragma unroll
    for (int ns = 0; ns < 2; ++ns) {
      int d = d0 + wn * 32 + ns * 16 + lrow;
#pragma unroll
      for (int r = 0; r < 4; ++r) {
        int bh = m0 + wm * 32 + ms * 16 + (lane >> 4) * 4 + r;
        int b = bh >> 4, h = bh & 15;
        long idx = (long)(b * T_ + q) * ND + h * DH + d;
        Yb[idx] += acc[ms][ns][r];
      }
    }
}

// ------------------- out = Yb @ Wp + bp -------------------
__global__ __launch_bounds__(256) void k_oproj(const float* __restrict__ Yb,
                                               const unsigned short* __restrict__ WpT,
                                               const float* __restrict__ bp,
                                               float* __restrict__ outp) {
  __shared__ unsigned short As[64][72], Bs[64][72];
  GEMM_IDS
  const int m0 = blockIdx.y * 64, n0 = blockIdx.x * 64;
  f32x4 acc[2][2] = {};
  for (int kk = 0; kk < ND; kk += 64) {
    stage_f32(As, Yb + (long)m0 * ND + kk, ND, tid);
    stage_b16(Bs, WpT + (long)n0 * ND + kk, ND, tid);
    __syncthreads();
    gemm_step(As, Bs, wm, wn, lrow, lk8, acc);
    __syncthreads();
  }
#pragma unroll
  for (int ms = 0; ms < 2; ++ms)
#pragma unroll
    for (int ns = 0; ns < 2; ++ns) {
      int n = n0 + wn * 32 + ns * 16 + lrow;
      float bias = bp[n];
#pragma unroll
      for (int r = 0; r < 4; ++r) {
        int m = m0 + wm * 32 + ms * 16 + (lane >> 4) * 4 + r;
        outp[(long)m * D_ + n] = acc[ms][ns][r] + bias;
      }
    }
}

extern "C" void kernel_launch(void* const* d_in, const int* in_sizes, int n_in,
                              void* d_out, int out_size, void* d_ws, size_t ws_size,
                              hipStream_t stream) {
  const float* X  = (const float*)d_in[0];
  const float* Pk = (const float*)d_in[1];
  const float* Pv = (const float*)d_in[2];
  const float* Wq = (const float*)d_in[3];
  const float* bq = (const float*)d_in[4];
  const float* Wk = (const float*)d_in[5];
  const float* bk = (const float*)d_in[6];
  const float* Wv = (const float*)d_in[7];
  const float* bv = (const float*)d_in[8];
  const float* Wp = (const float*)d_in[9];
  const float* bp = (const float*)d_in[10];
  float* out = (float*)d_out;

  uint8_t* w = (uint8_t*)d_ws;
  unsigned short* Xb  = (unsigned short*)w; w += (size_t)BT * D_ * 2;      //  8 MB
  unsigned short* WT  = (unsigned short*)w; w += (size_t)3 * ND * D_ * 2;  // 12 MB
  unsigned short* WpT = (unsigned short*)w; w += (size_t)D_ * ND * 2;      //  4 MB
  unsigned short* Qb  = (unsigned short*)w; w += (size_t)T_ * BH * DH * 2; // 16 MB
  unsigned short* Kb  = (unsigned short*)w; w += (size_t)T_ * BH * DH * 2; // 16 MB
  unsigned short* Vb  = (unsigned short*)w; w += (size_t)T_ * BH * DH * 2; // 16 MB
  unsigned short* Vt  = (unsigned short*)w; w += (size_t)BH * DH * T_ * 2; // 16 MB
  unsigned short* att = (unsigned short*)w; w += (size_t)T_ * BH * T_ * 2; // 67 MB (logits, then P in-place)
  float*          Yb  = (float*)w;          w += (size_t)B_ * T_ * ND * 4; // 33.5 MB

  k_cvt<<<BT * D_ / 4 / 256, 256, 0, stream>>>(X, Xb, BT * D_ / 4);
  k_transcvt<<<dim3(ND / 32, D_ / 32), 256, 0, stream>>>(Wq, WT, D_, ND);
  k_transcvt<<<dim3(ND / 32, D_ / 32), 256, 0, stream>>>(Wk, WT + (size_t)ND * D_, D_, ND);
  k_transcvt<<<dim3(ND / 32, D_ / 32), 256, 0, stream>>>(Wv, WT + (size_t)2 * ND * D_, D_, ND);
  k_transcvt<<<dim3(D_ / 32, ND / 32), 256, 0, stream>>>(Wp, WpT, ND, D_);
  k_proj<<<dim3(3 * ND / 64, BT / 64), 256, 0, stream>>>(Xb, WT, bq, bk, bv, Qb, Kb, Vb);
  k_vtrans<<<dim3(T_ / 32, DH / 32, BH), 256, 0, stream>>>(Vb, Vt);
  k_posk<<<dim3(T_ / 64, BH / 64, T_), 256, 0, stream>>>(Qb, Pk, att);
  k_qk<<<dim3(T_ / 64, T_ / 64, BH), 256, 0, stream>>>(Qb, Kb, att);
  k_softmax<<<T_ * BH / 4, 256, 0, stream>>>(att);
  k_attv<<<dim3(DH / 64, T_ / 64, BH), 256, 0, stream>>>(att, Vt, Yb);
  k_posv<<<dim3(DH / 64, BH / 64, T_), 256, 0, stream>>>(att, Pv, Yb);
  k_oproj<<<dim3(D_ / 64, BT / 64), 256, 0, stream>>>(Yb, WpT, bp, out);
}

// Round 2
// 373.107 us; speedup vs baseline: 1.1544x; 1.1544x over previous
//
#include <hip/hip_runtime.h>
#include <stdint.h>

#define B_  8
#define T_  512
#define D_  1024
#define H_  16
#define DH  128
#define BH  128          // B_*H_
#define ND  2048         // H_*DH
#define BT  4096         // B_*T_

typedef __attribute__((ext_vector_type(8))) short          short8;
typedef __attribute__((ext_vector_type(8))) __bf16         bf16x8;
typedef __attribute__((ext_vector_type(4))) float          f32x4;
typedef __attribute__((ext_vector_type(4))) unsigned short ushort4v;

static __device__ __forceinline__ unsigned short f2bf(float f) {
  unsigned u = __builtin_bit_cast(unsigned, f);
  u += 0x7FFFu + ((u >> 16) & 1u);           // round-to-nearest-even
  return (unsigned short)(u >> 16);
}
static __device__ __forceinline__ float bf2f(unsigned short h) {
  unsigned u = ((unsigned)h) << 16;
  return __builtin_bit_cast(float, u);
}
static __device__ __forceinline__ f32x4 mfma16(short8 a, short8 b, f32x4 c) {
  return __builtin_amdgcn_mfma_f32_16x16x32_bf16(
      __builtin_bit_cast(bf16x8, a), __builtin_bit_cast(bf16x8, b), c, 0, 0, 0);
}

// async global->LDS, 16B per lane. LDS dest must be linear in lane order.
static __device__ __forceinline__ void gload16(const unsigned short* g, unsigned short* l) {
  __builtin_amdgcn_global_load_lds(
      (const __attribute__((address_space(1))) void*)g,
      (__attribute__((address_space(3))) void*)l, 16, 0, 0);
}

// stage ROWS x 64 bf16 tile into linear LDS [ROWS][64] via global_load_lds
template <int ROWS>
static __device__ __forceinline__ void stage_gl(unsigned short* lds,
                                                const unsigned short* __restrict__ src,
                                                long stride, int tid) {
#pragma unroll
  for (int it = 0; it < ROWS / 32; ++it) {
    int chunk = tid + it * 256;               // 16B chunks
    int r = chunk >> 3, c8 = (chunk & 7) * 8;
    gload16(src + (long)r * stride + c8, lds + chunk * 8);
  }
}

// stage 64 x 64 fp32 -> bf16 into linear LDS [64][64] (reg-staged convert)
static __device__ __forceinline__ void stage_cvt64(unsigned short* lds,
                                                   const float* __restrict__ src,
                                                   long stride, int tid) {
#pragma unroll
  for (int it = 0; it < 4; ++it) {
    int chunk = tid + it * 256;               // 0..1023
    int r = chunk >> 4, c4 = (chunk & 15) * 4;
    f32x4 v = *(const f32x4*)(src + (long)r * stride + c4);
    ushort4v o; o.x = f2bf(v.x); o.y = f2bf(v.y); o.z = f2bf(v.z); o.w = f2bf(v.w);
    *(ushort4v*)(lds + r * 64 + c4) = o;
  }
}

// transpose-stage: src fp32 rows k(64) x 128 d, stride 128 -> dst [128 d][64 k] bf16
static __device__ __forceinline__ void stage_cvt_t128(unsigned short* lds,
                                                      const float* __restrict__ src,
                                                      int tid) {
#pragma unroll
  for (int it = 0; it < 8; ++it) {
    int chunk = tid + it * 256;               // 0..2047
    int k = chunk >> 5, d4 = (chunk & 31) * 4;
    f32x4 v = *(const f32x4*)(src + (long)k * DH + d4);
    lds[(d4 + 0) * 64 + k] = f2bf(v.x);
    lds[(d4 + 1) * 64 + k] = f2bf(v.y);
    lds[(d4 + 2) * 64 + k] = f2bf(v.z);
    lds[(d4 + 3) * 64 + k] = f2bf(v.w);
  }
}

// MR x NR 16x16 fragments over one BK=64 step; As/Bs linear [*][64]
template <int MR, int NR>
static __device__ __forceinline__ void mfma_block(const unsigned short* As,
                                                  const unsigned short* Bs,
                                                  int a0, int b0, int lrow, int lk8,
                                                  f32x4 acc[MR][NR]) {
#pragma unroll
  for (int ks = 0; ks < 64; ks += 32) {
    short8 a[MR], b[NR];
#pragma unroll
    for (int i = 0; i < MR; ++i) a[i] = *(const short8*)&As[(a0 + i * 16 + lrow) * 64 + ks + lk8];
#pragma unroll
    for (int j = 0; j < NR; ++j) b[j] = *(const short8*)&Bs[(b0 + j * 16 + lrow) * 64 + ks + lk8];
#pragma unroll
    for (int i = 0; i < MR; ++i)
#pragma unroll
      for (int j = 0; j < NR; ++j) acc[i][j] = mfma16(a[i], b[j], acc[i][j]);
  }
}

#define IDS4                             \
  const int tid  = threadIdx.x;          \
  const int lane = tid & 63;             \
  const int wid  = tid >> 6;             \
  const int lrow = lane & 15;            \
  const int lk8  = (lane >> 4) * 8;      \
  const int lr4  = (lane >> 4) * 4;

// ------------------- prep kernels -------------------
__global__ __launch_bounds__(256) void k_cvt(const float* __restrict__ in,
                                             unsigned short* __restrict__ outp, int n4) {
  int i = blockIdx.x * 256 + threadIdx.x;
  if (i >= n4) return;
  f32x4 v = ((const f32x4*)in)[i];
  ushort4v o;
  o.x = f2bf(v.x); o.y = f2bf(v.y); o.z = f2bf(v.z); o.w = f2bf(v.w);
  ((ushort4v*)outp)[i] = o;
}

__global__ __launch_bounds__(256) void k_transcvt(const float* __restrict__ in,
                                                  unsigned short* __restrict__ outp,
                                                  int R, int C) {
  __shared__ float tile[32][33];
  int c0 = blockIdx.x * 32, r0 = blockIdx.y * 32;
  int tx = threadIdx.x & 31, ty = threadIdx.x >> 5;
#pragma unroll
  for (int i = 0; i < 32; i += 8)
    tile[ty + i][tx] = in[(long)(r0 + ty + i) * C + (c0 + tx)];
  __syncthreads();
#pragma unroll
  for (int i = 0; i < 32; i += 8)
    outp[(long)(c0 + ty + i) * R + (r0 + tx)] = f2bf(tile[tx][ty + i]);
}

// Vb[t][bh][d] -> Vt[bh][d][t]
__global__ __launch_bounds__(256) void k_vtrans(const unsigned short* __restrict__ vin,
                                                unsigned short* __restrict__ vout) {
  __shared__ unsigned short tile[32][33];
  int bh = blockIdx.z;
  int t0 = blockIdx.x * 32, d0 = blockIdx.y * 32;
  int tx = threadIdx.x & 31, ty = threadIdx.x >> 5;
#pragma unroll
  for (int i = 0; i < 32; i += 8)
    tile[ty + i][tx] = vin[((long)(t0 + ty + i) * BH + bh) * DH + (d0 + tx)];
  __syncthreads();
#pragma unroll
  for (int i = 0; i < 32; i += 8)
    vout[((long)bh * DH + (d0 + ty + i)) * T_ + (t0 + tx)] = tile[tx][ty + i];
}

// ------------------- QKV projection: 128x128 tile, m97 structure -------------------
__global__ __launch_bounds__(256) void k_proj(const unsigned short* __restrict__ Xb,
                                              const unsigned short* __restrict__ WT,
                                              const float* __restrict__ bq,
                                              const float* __restrict__ bk,
                                              const float* __restrict__ bv,
                                              unsigned short* __restrict__ Qb,
                                              unsigned short* __restrict__ Kb,
                                              unsigned short* __restrict__ Vb) {
  __shared__ unsigned short As[128 * 64], Bs[128 * 64];
  IDS4
  const int wm = wid >> 1, wn = wid & 1;
  const int m0 = blockIdx.y * 128, n0 = blockIdx.x * 128;
  f32x4 acc[4][4] = {};
  for (int kk = 0; kk < D_; kk += 64) {
    stage_gl<128>(As, Xb + (long)m0 * D_ + kk, D_, tid);
    stage_gl<128>(Bs, WT + (long)n0 * D_ + kk, D_, tid);
    __syncthreads();
    mfma_block<4, 4>(As, Bs, wm * 64, wn * 64, lrow, lk8, acc);
    __syncthreads();
  }
  const int nb = n0 >> 11;   // 0:Q 1:K 2:V
  const float* biasp = nb == 0 ? bq : (nb == 1 ? bk : bv);
  unsigned short* dst = nb == 0 ? Qb : (nb == 1 ? Kb : Vb);
#pragma unroll
  for (int i = 0; i < 4; ++i)
#pragma unroll
    for (int j = 0; j < 4; ++j) {
      int n = n0 + wn * 64 + j * 16 + lrow;
      int nh = n & (ND - 1);
      int h = nh >> 7, dd = nh & (DH - 1);
      float bias = biasp[nh];
#pragma unroll
      for (int r = 0; r < 4; ++r) {
        int m = m0 + wm * 64 + i * 16 + lr4 + r;
        int b = m >> 9, t = m & (T_ - 1);
        dst[((long)t * BH + (b * H_ + h)) * DH + dd] = f2bf(acc[i][j][r] + bias);
      }
    }
}

// ------------------- pos-k: att[q][bh][k] = Q[q] . Pk[q], M=128(bh), N=64(k) -------------------
__global__ __launch_bounds__(256) void k_posk(const unsigned short* __restrict__ Qb,
                                              const float* __restrict__ Pk,
                                              unsigned short* __restrict__ att) {
  const int q = blockIdx.y, k0 = blockIdx.x * 64;
  if (k0 > q) return;
  __shared__ unsigned short As[128 * 64], Bs[64 * 64];
  IDS4
  const int wm = wid >> 1, wn = wid & 1;
  f32x4 acc[4][2] = {};
  for (int kk = 0; kk < DH; kk += 64) {
    stage_gl<128>(As, Qb + (long)q * BH * DH + kk, DH, tid);
    stage_cvt64(Bs, Pk + ((long)q * T_ + k0) * DH + kk, DH, tid);
    __syncthreads();
    mfma_block<4, 2>(As, Bs, wm * 64, wn * 32, lrow, lk8, acc);
    __syncthreads();
  }
#pragma unroll
  for (int i = 0; i < 4; ++i)
#pragma unroll
    for (int j = 0; j < 2; ++j) {
      int k = k0 + wn * 32 + j * 16 + lrow;
#pragma unroll
      for (int r = 0; r < 4; ++r) {
        int bh = wm * 64 + i * 16 + lr4 + r;
        att[((long)q * BH + bh) * T_ + k] = f2bf(acc[i][j][r]);
      }
    }
}

// ------------------- QK^T + pos bias + scale, M=128(q), N=64(k) -------------------
__global__ __launch_bounds__(256) void k_qk(const unsigned short* __restrict__ Qb,
                                            const unsigned short* __restrict__ Kb,
                                            unsigned short* __restrict__ att) {
  const int bh = blockIdx.z, q0 = blockIdx.y * 128, k0 = blockIdx.x * 64;
  if (k0 > q0 + 127) return;
  __shared__ unsigned short As[128 * 64], Bs[64 * 64];
  IDS4
  const int wm = wid >> 1, wn = wid & 1;
  f32x4 acc[4][2] = {};
  for (int kk = 0; kk < DH; kk += 64) {
    stage_gl<128>(As, Qb + ((long)q0 * BH + bh) * DH + kk, (long)BH * DH, tid);
    stage_gl<64>(Bs, Kb + ((long)k0 * BH + bh) * DH + kk, (long)BH * DH, tid);
    __syncthreads();
    mfma_block<4, 2>(As, Bs, wm * 64, wn * 32, lrow, lk8, acc);
    __syncthreads();
  }
  const float scale = 0.08838834764831845f;   // 1/sqrt(128)
#pragma unroll
  for (int i = 0; i < 4; ++i)
#pragma unroll
    for (int j = 0; j < 2; ++j) {
      int k = k0 + wn * 32 + j * 16 + lrow;
#pragma unroll
      for (int r = 0; r < 4; ++r) {
        int q = q0 + wm * 64 + i * 16 + lr4 + r;
        long idx = ((long)q * BH + bh) * T_ + k;
        float v = acc[i][j][r];
        if (k <= q) v += bf2f(att[idx]);
        att[idx] = f2bf(v * scale);
      }
    }
}

// ------------------- softmax (in-place, causal prefix only) -------------------
__global__ __launch_bounds__(256) void k_softmax(unsigned short* __restrict__ att) {
  const int lane = threadIdx.x & 63, wave = threadIdx.x >> 6;
  const long row = (long)blockIdx.x * 4 + wave;   // row = q*BH + bh
  const int q = (int)(row >> 7);
  const int len = ((q >> 6) + 1) << 6;
  unsigned short* p = att + row * T_;
  const bool act = lane * 8 < len;
  short8 v8 = {};
  if (act) v8 = *(const short8*)(p + lane * 8);
  float x[8];
  float m = -3.0e38f;
#pragma unroll
  for (int j = 0; j < 8; ++j) {
    int k = lane * 8 + j;
    x[j] = (act && k <= q) ? bf2f((unsigned short)v8[j]) : -3.0e38f;
    m = fmaxf(m, x[j]);
  }
#pragma unroll
  for (int off = 32; off >= 1; off >>= 1) m = fmaxf(m, __shfl_xor(m, off, 64));
  float e[8];
  float s = 0.f;
#pragma unroll
  for (int j = 0; j < 8; ++j) {
    int k = lane * 8 + j;
    e[j] = (act && k <= q) ? __expf(x[j] - m) : 0.f;
    s += e[j];
  }
#pragma unroll
  for (int off = 32; off >= 1; off >>= 1) s += __shfl_xor(s, off, 64);
  float inv = 1.f / s;
  if (act) {
    short8 o;
#pragma unroll
    for (int j = 0; j < 8; ++j) o[j] = (short)f2bf(e[j] * inv);
    *(short8*)(p + lane * 8) = o;
  }
}

// ------------------- y = P @ V, M=64(q), N=128(d), writes Yb fp32 -------------------
__global__ __launch_bounds__(256) void k_attv(const unsigned short* __restrict__ P,
                                              const unsigned short* __restrict__ Vt,
                                              float* __restrict__ Yb) {
  const int bh = blockIdx.y, qt = blockIdx.x;
  const int q0 = qt * 64;
  __shared__ unsigned short As[64 * 64], Bs[128 * 64];
  IDS4
  const int wm = wid >> 1, wn = wid & 1;
  f32x4 acc[2][4] = {};
  for (int kt = 0; kt <= qt; ++kt) {
    stage_gl<64>(As, P + ((long)q0 * BH + bh) * T_ + kt * 64, (long)BH * T_, tid);
    stage_gl<128>(Bs, Vt + (long)bh * DH * T_ + kt * 64, T_, tid);
    __syncthreads();
    mfma_block<2, 4>(As, Bs, wm * 32, wn * 64, lrow, lk8, acc);
    __syncthreads();
  }
  const int b = bh >> 4, h = bh & 15;
#pragma unroll
  for (int i = 0; i < 2; ++i)
#pragma unroll
    for (int j = 0; j < 4; ++j) {
      int d = wn * 64 + j * 16 + lrow;
#pragma unroll
      for (int r = 0; r < 4; ++r) {
        int q = q0 + wm * 32 + i * 16 + lr4 + r;
        Yb[(long)(b * T_ + q) * ND + h * DH + d] = acc[i][j][r];
      }
    }
}

// ------------------- y += P @ pos_v[q]; writes final bf16 Ybb. M=128(bh), N=128(d) -------------------
__global__ __launch_bounds__(256) void k_posv(const unsigned short* __restrict__ P,
                                              const float* __restrict__ Pv,
                                              const float* __restrict__ Yb,
                                              unsigned short* __restrict__ Ybb) {
  const int q = blockIdx.x;
  const int ktiles = (q >> 6) + 1;
  __shared__ unsigned short As[128 * 64], Bs[128 * 64];
  IDS4
  const int wm = wid >> 1, wn = wid & 1;
  f32x4 acc[4][4] = {};
  for (int kt = 0; kt < ktiles; ++kt) {
    stage_gl<128>(As, P + (long)q * BH * T_ + kt * 64, T_, tid);
    stage_cvt_t128(Bs, Pv + ((long)q * T_ + kt * 64) * DH, tid);
    __syncthreads();
    mfma_block<4, 4>(As, Bs, wm * 64, wn * 64, lrow, lk8, acc);
    __syncthreads();
  }
#pragma unroll
  for (int i = 0; i < 4; ++i)
#pragma unroll
    for (int j = 0; j < 4; ++j) {
      int d = wn * 64 + j * 16 + lrow;
#pragma unroll
      for (int r = 0; r < 4; ++r) {
        int bh = wm * 64 + i * 16 + lr4 + r;
        int b = bh >> 4, h = bh & 15;
        long idx = (long)(b * T_ + q) * ND + h * DH + d;
        Ybb[idx] = f2bf(Yb[idx] + acc[i][j][r]);
      }
    }
}

// ------------------- out = Ybb @ Wp + bp, M=128, N=64 -------------------
__global__ __launch_bounds__(256) void k_oproj(const unsigned short* __restrict__ Ybb,
                                               const unsigned short* __restrict__ WpT,
                                               const float* __restrict__ bp,
                                               float* __restrict__ outp) {
  __shared__ unsigned short As[128 * 64], Bs[64 * 64];
  IDS4
  const int wm = wid >> 1, wn = wid & 1;
  const int m0 = blockIdx.y * 128, n0 = blockIdx.x * 64;
  f32x4 acc[4][2] = {};
  for (int kk = 0; kk < ND; kk += 64) {
    stage_gl<128>(As, Ybb + (long)m0 * ND + kk, ND, tid);
    stage_gl<64>(Bs, WpT + (long)n0 * ND + kk, ND, tid);
    __syncthreads();
    mfma_block<4, 2>(As, Bs, wm * 64, wn * 32, lrow, lk8, acc);
    __syncthreads();
  }
#pragma unroll
  for (int i = 0; i < 4; ++i)
#pragma unroll
    for (int j = 0; j < 2; ++j) {
      int n = n0 + wn * 32 + j * 16 + lrow;
      float bias = bp[n];
#pragma unroll
      for (int r = 0; r < 4; ++r) {
        int m = m0 + wm * 64 + i * 16 + lr4 + r;
        outp[(long)m * D_ + n] = acc[i][j][r] + bias;
      }
    }
}

extern "C" void kernel_launch(void* const* d_in, const int* in_sizes, int n_in,
                              void* d_out, int out_size, void* d_ws, size_t ws_size,
                              hipStream_t stream) {
  const float* X  = (const float*)d_in[0];
  const float* Pk = (const float*)d_in[1];
  const float* Pv = (const float*)d_in[2];
  const float* Wq = (const float*)d_in[3];
  const float* bq = (const float*)d_in[4];
  const float* Wk = (const float*)d_in[5];
  const float* bk = (const float*)d_in[6];
  const float* Wv = (const float*)d_in[7];
  const float* bv = (const float*)d_in[8];
  const float* Wp = (const float*)d_in[9];
  const float* bp = (const float*)d_in[10];
  float* out = (float*)d_out;

  uint8_t* w = (uint8_t*)d_ws;
  unsigned short* Xb  = (unsigned short*)w; w += (size_t)BT * D_ * 2;      //  8 MB
  unsigned short* WT  = (unsigned short*)w; w += (size_t)3 * ND * D_ * 2;  // 12 MB
  unsigned short* WpT = (unsigned short*)w; w += (size_t)D_ * ND * 2;      //  4 MB
  unsigned short* Qb  = (unsigned short*)w; w += (size_t)T_ * BH * DH * 2; // 16 MB
  unsigned short* Kb  = (unsigned short*)w; w += (size_t)T_ * BH * DH * 2; // 16 MB
  unsigned short* Vb  = (unsigned short*)w; w += (size_t)T_ * BH * DH * 2; // 16 MB
  unsigned short* Vt  = (unsigned short*)w; w += (size_t)BH * DH * T_ * 2; // 16 MB
  unsigned short* att = (unsigned short*)w; w += (size_t)T_ * BH * T_ * 2; // 67 MB
  float*          Yb  = (float*)w;          w += (size_t)BT * ND * 4;      // 33.5 MB
  unsigned short* Ybb = (unsigned short*)w; w += (size_t)BT * ND * 2;      // 16.7 MB

  k_cvt<<<BT * D_ / 4 / 256, 256, 0, stream>>>(X, Xb, BT * D_ / 4);
  k_transcvt<<<dim3(ND / 32, D_ / 32), 256, 0, stream>>>(Wq, WT, D_, ND);
  k_transcvt<<<dim3(ND / 32, D_ / 32), 256, 0, stream>>>(Wk, WT + (size_t)ND * D_, D_, ND);
  k_transcvt<<<dim3(ND / 32, D_ / 32), 256, 0, stream>>>(Wv, WT + (size_t)2 * ND * D_, D_, ND);
  k_transcvt<<<dim3(D_ / 32, ND / 32), 256, 0, stream>>>(Wp, WpT, ND, D_);
  k_proj<<<dim3(3 * ND / 128, BT / 128), 256, 0, stream>>>(Xb, WT, bq, bk, bv, Qb, Kb, Vb);
  k_vtrans<<<dim3(T_ / 32, DH / 32, BH), 256, 0, stream>>>(Vb, Vt);
  k_posk<<<dim3(T_ / 64, T_), 256, 0, stream>>>(Qb, Pk, att);
  k_qk<<<dim3(T_ / 64, T_ / 128, BH), 256, 0, stream>>>(Qb, Kb, att);
  k_softmax<<<T_ * BH / 4, 256, 0, stream>>>(att);
  k_attv<<<dim3(T_ / 64, BH), 256, 0, stream>>>(att, Vt, Yb);
  k_posv<<<T_, 256, 0, stream>>>(att, Pv, Yb, Ybb);
  k_oproj<<<dim3(D_ / 64, BT / 128), 256, 0, stream>>>(Ybb, WpT, bp, out);
}